// Round 4
// baseline (1380.367 us; speedup 1.0000x reference)
//
#include <hip/hip_runtime.h>
#include <cfloat>
#include <math.h>

#define D_DIM 1024
#define B_DIM 4
#define NQ    1024
#define NC    16384
#define TOPN  5
#define TOPA  8               // stage-A candidates per context split
#define CSPLIT 8              // context splits per batch
#define CAND  (TOPA*CSPLIT)   // 64 candidates per query
#define QT    64              // queries per block (dist kernel)
#define CTILE 256             // contexts per tile iteration (dist kernel)
#define BK    64              // K per LDS stage (bf16 elements)
#define CSTR  72              // LDS row stride in shorts (144B: 16B-aligned, bank-balanced)

typedef __bf16 bf16x8 __attribute__((ext_vector_type(8)));
typedef float  f32x4  __attribute__((ext_vector_type(4)));
typedef short  short8 __attribute__((ext_vector_type(8)));

__device__ __forceinline__ unsigned short f2bf(float f) {
    unsigned u = __builtin_bit_cast(unsigned, f);
    unsigned r = (u + 0x7fffu + ((u >> 16) & 1u)) >> 16;
    return (unsigned short)r;
}

// ---- lexicographic (value, index) top-N insert (used by fp64 refine) ----
template<int N, typename T>
__device__ __forceinline__ void topk_insert(T (&bv)[N], int (&bi)[N], T v, int ci) {
    if (v < bv[N-1] || (v == bv[N-1] && ci < bi[N-1])) {
        bv[N-1] = v; bi[N-1] = ci;
        #pragma unroll
        for (int s = N-1; s > 0; --s) {
            bool sw = (bv[s] < bv[s-1]) || (bv[s] == bv[s-1] && bi[s] < bi[s-1]);
            if (sw) {
                T tv = bv[s-1]; bv[s-1] = bv[s]; bv[s] = tv;
                int ti = bi[s-1]; bi[s-1] = bi[s]; bi[s] = ti;
            }
        }
    }
}

// ---- value-only top-8 insert (screening; ties resolved by fp64 refine) ----
__device__ __forceinline__ void ins8(float (&bv)[TOPA], int (&bi)[TOPA], float v, int ci) {
    if (v < bv[TOPA-1]) {
        bv[TOPA-1] = v; bi[TOPA-1] = ci;
        #pragma unroll
        for (int s = TOPA-1; s > 0; --s) {
            if (bv[s] < bv[s-1]) {
                float tv = bv[s-1]; bv[s-1] = bv[s]; bv[s] = tv;
                int   ti = bi[s-1]; bi[s-1] = bi[s]; bi[s] = ti;
            }
        }
    }
}

// ---- Kernel 1: P64[m][e] = sum_d Q[m][d]*W[e][d] + b[e] in fp64 (exact ranking basis) ----
__global__ __launch_bounds__(256) void proj64_kernel(const float* __restrict__ Q,
                                                     const float* __restrict__ W,
                                                     const float* __restrict__ bias,
                                                     double* __restrict__ P64)
{
    __shared__ float Qs[32][64];
    __shared__ float Ws[32][64];
    const int m0 = blockIdx.y * 64;
    const int n0 = blockIdx.x * 64;
    const int t  = threadIdx.x;
    const int tm = t >> 4;
    const int tn = t & 15;
    double acc[4][4] = {};
    for (int k0 = 0; k0 < D_DIM; k0 += 32) {
        #pragma unroll
        for (int r = 0; r < 2; ++r) {
            int idx = t + r * 256;
            int row = idx >> 3;
            int kc  = idx & 7;
            float4 qa = *(const float4*)&Q[(size_t)(m0 + row) * D_DIM + k0 + kc * 4];
            float4 wa = *(const float4*)&W[(size_t)(n0 + row) * D_DIM + k0 + kc * 4];
            Qs[kc*4+0][row] = qa.x; Qs[kc*4+1][row] = qa.y; Qs[kc*4+2][row] = qa.z; Qs[kc*4+3][row] = qa.w;
            Ws[kc*4+0][row] = wa.x; Ws[kc*4+1][row] = wa.y; Ws[kc*4+2][row] = wa.z; Ws[kc*4+3][row] = wa.w;
        }
        __syncthreads();
        #pragma unroll
        for (int kk = 0; kk < 32; ++kk) {
            float4 a = *(const float4*)&Qs[kk][tm * 4];
            float4 w = *(const float4*)&Ws[kk][tn * 4];
            double av[4] = {a.x, a.y, a.z, a.w};
            double wv[4] = {w.x, w.y, w.z, w.w};
            #pragma unroll
            for (int i = 0; i < 4; ++i)
                #pragma unroll
                for (int j = 0; j < 4; ++j)
                    acc[i][j] = fma(av[i], wv[j], acc[i][j]);
        }
        __syncthreads();
    }
    #pragma unroll
    for (int i = 0; i < 4; ++i)
        #pragma unroll
        for (int j = 0; j < 4; ++j)
            P64[(size_t)(m0 + tm * 4 + i) * D_DIM + n0 + tn * 4 + j] =
                acc[i][j] + (double)bias[n0 + tn * 4 + j];
}

// ---- Kernel 2: pack C -> bf16 + fp32 row squared norms (single pass over C) ----
__global__ __launch_bounds__(256) void pack_c_kernel(const float* __restrict__ C,
                                                     unsigned short* __restrict__ Cbf,
                                                     float* __restrict__ csq)
{
    int wave = threadIdx.x >> 6;
    int lane = threadIdx.x & 63;
    int row  = blockIdx.x * 4 + wave;
    const float* x = C + (size_t)row * D_DIM;
    float s = 0.f;
    #pragma unroll
    for (int i = 0; i < 4; ++i) {
        float4 v = *(const float4*)&x[lane * 4 + i * 256];
        s += v.x * v.x + v.y * v.y + v.z * v.z + v.w * v.w;
        ushort4 h;
        h.x = f2bf(v.x); h.y = f2bf(v.y); h.z = f2bf(v.z); h.w = f2bf(v.w);
        *(ushort4*)&Cbf[(size_t)row * D_DIM + lane * 4 + i * 256] = h;
    }
    #pragma unroll
    for (int off = 32; off; off >>= 1) s += __shfl_down(s, off, 64);
    if (lane == 0) csq[row] = s;
}

// ---- Kernel 3: pack P64 -> bf16 Pbf + fp32 qsq ----
__global__ __launch_bounds__(256) void pack_q_kernel(const double* __restrict__ P64,
                                                     unsigned short* __restrict__ Pbf,
                                                     float* __restrict__ qsq)
{
    int wave = threadIdx.x >> 6;
    int lane = threadIdx.x & 63;
    int row  = blockIdx.x * 4 + wave;
    const double* x = P64 + (size_t)row * D_DIM;
    float s = 0.f;
    #pragma unroll
    for (int j = 0; j < 8; ++j) {
        double2 v = *(const double2*)&x[lane * 2 + j * 128];
        float a = (float)v.x, b = (float)v.y;
        s += a * a + b * b;
        ushort2 h; h.x = f2bf(a); h.y = f2bf(b);
        *(ushort2*)&Pbf[(size_t)row * D_DIM + lane * 2 + j * 128] = h;
    }
    #pragma unroll
    for (int off = 32; off; off >>= 1) s += __shfl_down(s, off, 64);
    if (lane == 0) qsq[row] = s;
}

// ---- Kernel 4: bf16-MFMA screening GEMM + per-lane register top-8 ----
// grid: (CSPLIT, NQ/QT, B), block 256 = 4 waves.
// Block tile: 64 queries x 256 contexts/iter. Wave w: contexts w*64..+63, all 64 queries.
// MFMA 16x16x32_bf16: A = contexts (m: row=(lane>>4)*4+reg), B = queries (n: col=lane&15).
__global__ __launch_bounds__(256) void dist_mfma_kernel(const unsigned short* __restrict__ Pbf,
                                                        const unsigned short* __restrict__ Cbf,
                                                        const float* __restrict__ qsq,
                                                        const float* __restrict__ csq,
                                                        int* __restrict__ pi)
{
    __shared__ __align__(16) short CsS[CTILE * CSTR];  // 36864 B
    __shared__ __align__(16) short QsS[QT * CSTR];     //  9216 B
    float* MV = (float*)CsS;                           // merge alias: [64][4][8]
    int*   MI = (int*)(CsS + 8192);                    // (8 KB offset in shorts = 16 KB bytes)

    const int t    = threadIdx.x;
    const int lane = t & 63;
    const int w    = t >> 6;       // wave 0..3 -> context quarter
    const int l15  = lane & 15;
    const int l4   = lane >> 4;    // 0..3
    const int csplit = blockIdx.x;
    const int by = blockIdx.y;
    const int bz = blockIdx.z;
    const int qg0 = bz * NQ + by * QT;

    float qsv[4];
    #pragma unroll
    for (int s = 0; s < 4; ++s) qsv[s] = qsq[qg0 + s * 16 + l15];

    float bv[4][TOPA]; int bi[4][TOPA];
    #pragma unroll
    for (int s = 0; s < 4; ++s)
        #pragma unroll
        for (int j = 0; j < TOPA; ++j) { bv[s][j] = FLT_MAX; bi[s][j] = 0x7fffffff; }

    const int cpb = NC / CSPLIT;   // 2048
    for (int it = 0; it < cpb / CTILE; ++it) {
        const int cg0 = csplit * cpb + it * CTILE;
        const size_t crow0 = (size_t)bz * NC + cg0;

        f32x4 acc[4][4];
        #pragma unroll
        for (int u = 0; u < 4; ++u)
            #pragma unroll
            for (int s = 0; s < 4; ++s) acc[u][s] = (f32x4)0.0f;

        for (int k0 = 0; k0 < D_DIM; k0 += BK) {
            // issue global loads first (overlap with previous MFMA / barrier)
            short8 creg[8], qreg[2];
            #pragma unroll
            for (int r = 0; r < 8; ++r) {
                int idx = t + r * 256;            // 0..2047
                int row = idx >> 3, ch = idx & 7;
                creg[r] = *(const short8*)&Cbf[(crow0 + row) * (size_t)D_DIM + k0 + ch * 8];
            }
            #pragma unroll
            for (int r = 0; r < 2; ++r) {
                int idx = t + r * 256;            // 0..511
                int row = idx >> 3, ch = idx & 7;
                qreg[r] = *(const short8*)&Pbf[(size_t)(qg0 + row) * D_DIM + k0 + ch * 8];
            }
            __syncthreads();   // previous iteration's LDS reads complete
            #pragma unroll
            for (int r = 0; r < 8; ++r) {
                int idx = t + r * 256;
                int row = idx >> 3, ch = idx & 7;
                *(short8*)&CsS[row * CSTR + ch * 8] = creg[r];
            }
            #pragma unroll
            for (int r = 0; r < 2; ++r) {
                int idx = t + r * 256;
                int row = idx >> 3, ch = idx & 7;
                *(short8*)&QsS[row * CSTR + ch * 8] = qreg[r];
            }
            __syncthreads();
            #pragma unroll
            for (int ks = 0; ks < 2; ++ks) {
                const int kb = (ks * 4 + l4) * 8;   // short offset within row
                bf16x8 bq[4], ac[4];
                #pragma unroll
                for (int s = 0; s < 4; ++s)
                    bq[s] = *(const bf16x8*)&QsS[(s * 16 + l15) * CSTR + kb];
                #pragma unroll
                for (int u = 0; u < 4; ++u)
                    ac[u] = *(const bf16x8*)&CsS[(w * 64 + u * 16 + l15) * CSTR + kb];
                #pragma unroll
                for (int u = 0; u < 4; ++u)
                    #pragma unroll
                    for (int s = 0; s < 4; ++s)
                        acc[u][s] = __builtin_amdgcn_mfma_f32_16x16x32_bf16(ac[u], bq[s], acc[u][s], 0, 0, 0);
            }
        }

        // d^2 = |q|^2 + |c|^2 - 2 q.c  -> per-lane register top-8 per query column
        #pragma unroll
        for (int u = 0; u < 4; ++u) {
            const int crow = w * 64 + u * 16 + l4 * 4;
            float4 cs4 = *(const float4*)&csq[(size_t)bz * NC + cg0 + crow];
            float csa[4] = {cs4.x, cs4.y, cs4.z, cs4.w};
            #pragma unroll
            for (int s = 0; s < 4; ++s) {
                #pragma unroll
                for (int r = 0; r < 4; ++r) {
                    float v = qsv[s] + csa[r] - 2.0f * acc[u][s][r];
                    ins8(bv[s], bi[s], v, cg0 + crow + r);
                }
            }
        }
    }

    // wave-level merge across l4 groups (same query columns) via shuffles
    #pragma unroll
    for (int mask = 16; mask <= 32; mask <<= 1) {
        #pragma unroll
        for (int s = 0; s < 4; ++s) {
            float ov[TOPA]; int oi[TOPA];
            #pragma unroll
            for (int j = 0; j < TOPA; ++j) {
                ov[j] = __shfl_xor(bv[s][j], mask, 64);
                oi[j] = __shfl_xor(bi[s][j], mask, 64);
            }
            #pragma unroll
            for (int j = 0; j < TOPA; ++j) ins8(bv[s], bi[s], ov[j], oi[j]);
        }
    }
    // cross-wave merge via LDS (l4==0 lanes hold wave-merged lists)
    __syncthreads();
    if (l4 == 0) {
        #pragma unroll
        for (int s = 0; s < 4; ++s) {
            int q = s * 16 + l15;
            #pragma unroll
            for (int j = 0; j < TOPA; ++j) {
                MV[(q * 4 + w) * TOPA + j] = bv[s][j];
                MI[(q * 4 + w) * TOPA + j] = bi[s][j];
            }
        }
    }
    __syncthreads();
    if (t < QT) {
        float mv[TOPA]; int mi[TOPA];
        #pragma unroll
        for (int j = 0; j < TOPA; ++j) { mv[j] = FLT_MAX; mi[j] = 0x7fffffff; }
        for (int l = 0; l < 4; ++l)
            #pragma unroll
            for (int j = 0; j < TOPA; ++j)
                ins8(mv, mi, MV[(t * 4 + l) * TOPA + j], MI[(t * 4 + l) * TOPA + j]);
        size_t base = (((size_t)qg0 + t) * CSPLIT + csplit) * TOPA;
        #pragma unroll
        for (int j = 0; j < TOPA; ++j) pi[base + j] = mi[j];
    }
}

// ---- Kernel 5: fp64 exact refine of 64 candidates per query -> top-5, sqrt, outputs ----
__global__ __launch_bounds__(256) void refine_kernel(const double* __restrict__ P64,
                                                     const float* __restrict__ C,
                                                     const int*   __restrict__ pi,
                                                     float* __restrict__ out)
{
    __shared__ double dvs[CAND];
    __shared__ int    dis[CAND];
    const int q    = blockIdx.x;
    const int bz   = q >> 10;
    const int t    = threadIdx.x;
    const int wave = t >> 6;
    const int lane = t & 63;
    const double* p = P64 + (size_t)q * D_DIM;

    for (int k = wave; k < CAND; k += 4) {
        int ci = pi[(size_t)q * CAND + k];
        const float* c = C + ((size_t)bz * NC + ci) * D_DIM;
        double s = 0.0;
        #pragma unroll
        for (int j = 0; j < 16; ++j) {
            int d = lane + 64 * j;
            double diff = p[d] - (double)c[d];
            s = fma(diff, diff, s);
        }
        #pragma unroll
        for (int off = 32; off; off >>= 1) s += __shfl_down(s, off, 64);
        if (lane == 0) { dvs[k] = s; dis[k] = ci; }
    }
    __syncthreads();
    if (t == 0) {
        double bv[TOPN]; int bi[TOPN];
        #pragma unroll
        for (int j = 0; j < TOPN; ++j) { bv[j] = DBL_MAX; bi[j] = 0x7fffffff; }
        for (int k = 0; k < CAND; ++k)
            topk_insert<TOPN,double>(bv, bi, dvs[k], dis[k]);
        #pragma unroll
        for (int j = 0; j < TOPN; ++j) {
            out[(size_t)q * TOPN + j] = (float)sqrt(bv[j]);
            out[(size_t)B_DIM * NQ * TOPN + (size_t)q * TOPN + j] = (float)bi[j];
        }
    }
}

extern "C" void kernel_launch(void* const* d_in, const int* in_sizes, int n_in,
                              void* d_out, int out_size, void* d_ws, size_t ws_size,
                              hipStream_t stream) {
    const float* Q    = (const float*)d_in[0];
    const float* C    = (const float*)d_in[1];
    const float* W    = (const float*)d_in[2];
    const float* bias = (const float*)d_in[3];
    float* out = (float*)d_out;

    char* ws = (char*)d_ws;
    double*         P64 = (double*)ws;                                       // 32 MB
    unsigned short* Pbf = (unsigned short*)(ws + (size_t)32 * 1024 * 1024);  //  8 MB
    unsigned short* Cbf = (unsigned short*)(ws + (size_t)40 * 1024 * 1024);  // 128 MB
    float*          qsq = (float*)(ws + (size_t)168 * 1024 * 1024);          // 16 KB
    float*          csq = qsq + 4096;                                        // 256 KB
    int*            pi  = (int*)(csq + 65536);                               // 1 MB
    // total ~169.3 MB of workspace

    proj64_kernel<<<dim3(D_DIM / 64, (B_DIM * NQ) / 64), 256, 0, stream>>>(Q, W, bias, P64);
    pack_c_kernel<<<(B_DIM * NC) / 4, 256, 0, stream>>>(C, Cbf, csq);
    pack_q_kernel<<<(B_DIM * NQ) / 4, 256, 0, stream>>>(P64, Pbf, qsq);
    dist_mfma_kernel<<<dim3(CSPLIT, NQ / QT, B_DIM), 256, 0, stream>>>(Pbf, Cbf, qsq, csq, pi);
    refine_kernel<<<B_DIM * NQ, 256, 0, stream>>>(P64, C, pi, out);
}

// Round 5
// 1120.584 us; speedup vs baseline: 1.2318x; 1.2318x over previous
//
#include <hip/hip_runtime.h>
#include <cfloat>
#include <math.h>

#define D_DIM 1024
#define B_DIM 4
#define NQ    1024
#define NC    16384
#define TOPN  5
#define TOPA  5               // stage-A candidates per context split
#define CSPLIT 16             // context splits per batch
#define CAND  (TOPA*CSPLIT)   // 80 candidates per query
#define QT    64              // queries per block (dist kernel)
#define CTILE 256             // contexts per tile iteration (dist kernel)
#define BK    64              // K per LDS stage (bf16 elements)

typedef __bf16 bf16x8 __attribute__((ext_vector_type(8)));
typedef float  f32x4  __attribute__((ext_vector_type(4)));

__device__ __forceinline__ unsigned short f2bf(float f) {
    unsigned u = __builtin_bit_cast(unsigned, f);
    unsigned r = (u + 0x7fffu + ((u >> 16) & 1u)) >> 16;
    return (unsigned short)r;
}

// async global->LDS, 16B per lane; LDS dest = wave-uniform base + lane*16
__device__ __forceinline__ void gload16(const void* g, void* l) {
    __builtin_amdgcn_global_load_lds(
        (const __attribute__((address_space(1))) unsigned*)g,
        (__attribute__((address_space(3))) unsigned*)l, 16, 0, 0);
}

// ---- lexicographic (value, index) top-N insert (used by fp64 refine) ----
template<int N, typename T>
__device__ __forceinline__ void topk_insert(T (&bv)[N], int (&bi)[N], T v, int ci) {
    if (v < bv[N-1] || (v == bv[N-1] && ci < bi[N-1])) {
        bv[N-1] = v; bi[N-1] = ci;
        #pragma unroll
        for (int s = N-1; s > 0; --s) {
            bool sw = (bv[s] < bv[s-1]) || (bv[s] == bv[s-1] && bi[s] < bi[s-1]);
            if (sw) {
                T tv = bv[s-1]; bv[s-1] = bv[s]; bv[s] = tv;
                int ti = bi[s-1]; bi[s-1] = bi[s]; bi[s] = ti;
            }
        }
    }
}

// ---- value-only top-N insert (screening; ties resolved by fp64 refine) ----
template<int N>
__device__ __forceinline__ void insN(float (&bv)[N], int (&bi)[N], float v, int ci) {
    if (v < bv[N-1]) {
        bv[N-1] = v; bi[N-1] = ci;
        #pragma unroll
        for (int s = N-1; s > 0; --s) {
            if (bv[s] < bv[s-1]) {
                float tv = bv[s-1]; bv[s-1] = bv[s]; bv[s] = tv;
                int   ti = bi[s-1]; bi[s-1] = bi[s]; bi[s] = ti;
            }
        }
    }
}

// ---- Kernel 1: P64[m][e] = sum_d Q[m][d]*W[e][d] + b[e] in fp64 (exact ranking basis) ----
__global__ __launch_bounds__(256) void proj64_kernel(const float* __restrict__ Q,
                                                     const float* __restrict__ W,
                                                     const float* __restrict__ bias,
                                                     double* __restrict__ P64)
{
    __shared__ float Qs[32][64];
    __shared__ float Ws[32][64];
    const int m0 = blockIdx.y * 64;
    const int n0 = blockIdx.x * 64;
    const int t  = threadIdx.x;
    const int tm = t >> 4;
    const int tn = t & 15;
    double acc[4][4] = {};
    for (int k0 = 0; k0 < D_DIM; k0 += 32) {
        #pragma unroll
        for (int r = 0; r < 2; ++r) {
            int idx = t + r * 256;
            int row = idx >> 3;
            int kc  = idx & 7;
            float4 qa = *(const float4*)&Q[(size_t)(m0 + row) * D_DIM + k0 + kc * 4];
            float4 wa = *(const float4*)&W[(size_t)(n0 + row) * D_DIM + k0 + kc * 4];
            Qs[kc*4+0][row] = qa.x; Qs[kc*4+1][row] = qa.y; Qs[kc*4+2][row] = qa.z; Qs[kc*4+3][row] = qa.w;
            Ws[kc*4+0][row] = wa.x; Ws[kc*4+1][row] = wa.y; Ws[kc*4+2][row] = wa.z; Ws[kc*4+3][row] = wa.w;
        }
        __syncthreads();
        #pragma unroll
        for (int kk = 0; kk < 32; ++kk) {
            float4 a = *(const float4*)&Qs[kk][tm * 4];
            float4 w = *(const float4*)&Ws[kk][tn * 4];
            double av[4] = {a.x, a.y, a.z, a.w};
            double wv[4] = {w.x, w.y, w.z, w.w};
            #pragma unroll
            for (int i = 0; i < 4; ++i)
                #pragma unroll
                for (int j = 0; j < 4; ++j)
                    acc[i][j] = fma(av[i], wv[j], acc[i][j]);
        }
        __syncthreads();
    }
    #pragma unroll
    for (int i = 0; i < 4; ++i)
        #pragma unroll
        for (int j = 0; j < 4; ++j)
            P64[(size_t)(m0 + tm * 4 + i) * D_DIM + n0 + tn * 4 + j] =
                acc[i][j] + (double)bias[n0 + tn * 4 + j];
}

// ---- Kernel 2: pack C -> bf16 + fp32 row squared norms (single pass over C) ----
__global__ __launch_bounds__(256) void pack_c_kernel(const float* __restrict__ C,
                                                     unsigned short* __restrict__ Cbf,
                                                     float* __restrict__ csq)
{
    int wave = threadIdx.x >> 6;
    int lane = threadIdx.x & 63;
    int row  = blockIdx.x * 4 + wave;
    const float* x = C + (size_t)row * D_DIM;
    float s = 0.f;
    #pragma unroll
    for (int i = 0; i < 4; ++i) {
        float4 v = *(const float4*)&x[lane * 4 + i * 256];
        s += v.x * v.x + v.y * v.y + v.z * v.z + v.w * v.w;
        ushort4 h;
        h.x = f2bf(v.x); h.y = f2bf(v.y); h.z = f2bf(v.z); h.w = f2bf(v.w);
        *(ushort4*)&Cbf[(size_t)row * D_DIM + lane * 4 + i * 256] = h;
    }
    #pragma unroll
    for (int off = 32; off; off >>= 1) s += __shfl_down(s, off, 64);
    if (lane == 0) csq[row] = s;
}

// ---- Kernel 3: pack P64 -> bf16 Pbf + fp32 qsq ----
__global__ __launch_bounds__(256) void pack_q_kernel(const double* __restrict__ P64,
                                                     unsigned short* __restrict__ Pbf,
                                                     float* __restrict__ qsq)
{
    int wave = threadIdx.x >> 6;
    int lane = threadIdx.x & 63;
    int row  = blockIdx.x * 4 + wave;
    const double* x = P64 + (size_t)row * D_DIM;
    float s = 0.f;
    #pragma unroll
    for (int j = 0; j < 8; ++j) {
        double2 v = *(const double2*)&x[lane * 2 + j * 128];
        float a = (float)v.x, b = (float)v.y;
        s += a * a + b * b;
        ushort2 h; h.x = f2bf(a); h.y = f2bf(b);
        *(ushort2*)&Pbf[(size_t)row * D_DIM + lane * 2 + j * 128] = h;
    }
    #pragma unroll
    for (int off = 32; off; off >>= 1) s += __shfl_down(s, off, 64);
    if (lane == 0) qsq[row] = s;
}

// ---- Kernel 4: bf16-MFMA screening GEMM + per-lane register top-5 ----
// grid: (CSPLIT, NQ/QT, B), block 256 = 4 waves. Block tile: 64 q x 256 c/iter.
// Wave w owns contexts w*64..+63, all 64 queries (4x4 fragment tile = 16 MFMA / 8 ds_read).
// Staging via global_load_lds(16B) with source-side XOR swizzle:
//   LDS row r (64 shorts, unpadded) holds chunk ck at position ck^(r&7)
//   -> ds_read_b128 of fragment (l15 rows x chunk ks*4+l4) is bank-conflict-free.
__global__ __launch_bounds__(256, 3) void dist_mfma_kernel(const unsigned short* __restrict__ Pbf,
                                                           const unsigned short* __restrict__ Cbf,
                                                           const float* __restrict__ qsq,
                                                           const float* __restrict__ csq,
                                                           int* __restrict__ pi)
{
    __shared__ __align__(16) short CsS[CTILE * 64];  // 32 KB
    __shared__ __align__(16) short QsS[QT * 64];     //  8 KB
    float* MV = (float*)CsS;                         // merge alias: [64][4][TOPA]
    int*   MI = (int*)(CsS + 4096);                  // 8 KB offset

    const int t    = threadIdx.x;
    const int lane = t & 63;
    const int w    = t >> 6;       // wave 0..3 -> context quarter
    const int l15  = lane & 15;
    const int l4   = lane >> 4;    // 0..3
    const int r8   = lane >> 3;    // 0..7 (staging sub-row)
    const int sc   = lane & 7;     // staging store-chunk
    const int csplit = blockIdx.x;
    const int by = blockIdx.y;
    const int bz = blockIdx.z;
    const int qg0 = bz * NQ + by * QT;

    // loop-invariant lane-relative staging offsets (elements)
    unsigned cOff[8], qOff[2];
    #pragma unroll
    for (int j = 0; j < 8; ++j)
        cOff[j] = (unsigned)((w * 64 + j * 8 + r8) * D_DIM + (sc ^ r8) * 8);
    #pragma unroll
    for (int j = 0; j < 2; ++j)
        qOff[j] = (unsigned)((w * 16 + j * 8 + r8) * D_DIM + (sc ^ r8) * 8);

    float qsv[4];
    #pragma unroll
    for (int s = 0; s < 4; ++s) qsv[s] = qsq[qg0 + s * 16 + l15];

    float bv[4][TOPA]; int bi[4][TOPA];
    #pragma unroll
    for (int s = 0; s < 4; ++s)
        #pragma unroll
        for (int j = 0; j < TOPA; ++j) { bv[s][j] = FLT_MAX; bi[s][j] = 0x7fffffff; }

    const int cpb = NC / CSPLIT;   // 1024
    for (int it = 0; it < cpb / CTILE; ++it) {
        const int cg0 = csplit * cpb + it * CTILE;
        const size_t crow0 = (size_t)bz * NC + cg0;

        f32x4 acc[4][4];
        #pragma unroll
        for (int u = 0; u < 4; ++u)
            #pragma unroll
            for (int s = 0; s < 4; ++s) acc[u][s] = (f32x4)0.0f;

        for (int k0 = 0; k0 < D_DIM; k0 += BK) {
            const unsigned short* cB = Cbf + crow0 * D_DIM + k0;
            const unsigned short* qB = Pbf + (size_t)qg0 * D_DIM + k0;
            __syncthreads();   // all waves done reading previous LDS contents
            #pragma unroll
            for (int j = 0; j < 8; ++j)
                gload16(cB + cOff[j], &CsS[(w * 64 + j * 8) * 64]);
            #pragma unroll
            for (int j = 0; j < 2; ++j)
                gload16(qB + qOff[j], &QsS[(w * 16 + j * 8) * 64]);
            __syncthreads();   // vmcnt drained before barrier -> LDS filled
            #pragma unroll
            for (int ks = 0; ks < 2; ++ks) {
                const int sp = ((ks * 4 + l4) ^ (l15 & 7)) * 8;
                bf16x8 bq[4], ac[4];
                #pragma unroll
                for (int s = 0; s < 4; ++s)
                    bq[s] = *(const bf16x8*)&QsS[(s * 16 + l15) * 64 + sp];
                #pragma unroll
                for (int u = 0; u < 4; ++u)
                    ac[u] = *(const bf16x8*)&CsS[(w * 64 + u * 16 + l15) * 64 + sp];
                #pragma unroll
                for (int u = 0; u < 4; ++u)
                    #pragma unroll
                    for (int s = 0; s < 4; ++s)
                        acc[u][s] = __builtin_amdgcn_mfma_f32_16x16x32_bf16(ac[u], bq[s], acc[u][s], 0, 0, 0);
            }
        }

        // d^2 = |q|^2 + |c|^2 - 2 q.c  -> per-lane register top-5 per query column
        #pragma unroll
        for (int u = 0; u < 4; ++u) {
            const int crow = w * 64 + u * 16 + l4 * 4;
            float4 cs4 = *(const float4*)&csq[(size_t)bz * NC + cg0 + crow];
            float csa[4] = {cs4.x, cs4.y, cs4.z, cs4.w};
            #pragma unroll
            for (int s = 0; s < 4; ++s) {
                #pragma unroll
                for (int r = 0; r < 4; ++r) {
                    float v = qsv[s] + csa[r] - 2.0f * acc[u][s][r];
                    insN<TOPA>(bv[s], bi[s], v, cg0 + crow + r);
                }
            }
        }
    }

    // wave-level merge across l4 groups (same query columns) via shuffles
    #pragma unroll
    for (int mask = 16; mask <= 32; mask <<= 1) {
        #pragma unroll
        for (int s = 0; s < 4; ++s) {
            float ov[TOPA]; int oi[TOPA];
            #pragma unroll
            for (int j = 0; j < TOPA; ++j) {
                ov[j] = __shfl_xor(bv[s][j], mask, 64);
                oi[j] = __shfl_xor(bi[s][j], mask, 64);
            }
            #pragma unroll
            for (int j = 0; j < TOPA; ++j) insN<TOPA>(bv[s], bi[s], ov[j], oi[j]);
        }
    }
    // cross-wave merge via LDS (l4==0 lanes hold wave-merged lists)
    __syncthreads();
    if (l4 == 0) {
        #pragma unroll
        for (int s = 0; s < 4; ++s) {
            int q = s * 16 + l15;
            #pragma unroll
            for (int j = 0; j < TOPA; ++j) {
                MV[(q * 4 + w) * TOPA + j] = bv[s][j];
                MI[(q * 4 + w) * TOPA + j] = bi[s][j];
            }
        }
    }
    __syncthreads();
    if (t < QT) {
        float mv[TOPA]; int mi[TOPA];
        #pragma unroll
        for (int j = 0; j < TOPA; ++j) { mv[j] = FLT_MAX; mi[j] = 0x7fffffff; }
        for (int l = 0; l < 4; ++l)
            #pragma unroll
            for (int j = 0; j < TOPA; ++j)
                insN<TOPA>(mv, mi, MV[(t * 4 + l) * TOPA + j], MI[(t * 4 + l) * TOPA + j]);
        size_t base = (((size_t)qg0 + t) * CSPLIT + csplit) * TOPA;
        #pragma unroll
        for (int j = 0; j < TOPA; ++j) pi[base + j] = mi[j];
    }
}

// ---- Kernel 5: fp64 exact refine of 80 candidates per query -> top-5, sqrt, outputs ----
__global__ __launch_bounds__(256) void refine_kernel(const double* __restrict__ P64,
                                                     const float* __restrict__ C,
                                                     const int*   __restrict__ pi,
                                                     float* __restrict__ out)
{
    __shared__ double dvs[CAND];
    __shared__ int    dis[CAND];
    const int q    = blockIdx.x;
    const int bz   = q >> 10;
    const int t    = threadIdx.x;
    const int wave = t >> 6;
    const int lane = t & 63;
    const double* p = P64 + (size_t)q * D_DIM;

    for (int k = wave; k < CAND; k += 4) {
        int ci = pi[(size_t)q * CAND + k];
        const float* c = C + ((size_t)bz * NC + ci) * D_DIM;
        double s = 0.0;
        #pragma unroll
        for (int j = 0; j < 16; ++j) {
            int d = lane + 64 * j;
            double diff = p[d] - (double)c[d];
            s = fma(diff, diff, s);
        }
        #pragma unroll
        for (int off = 32; off; off >>= 1) s += __shfl_down(s, off, 64);
        if (lane == 0) { dvs[k] = s; dis[k] = ci; }
    }
    __syncthreads();
    if (t == 0) {
        double bv[TOPN]; int bi[TOPN];
        #pragma unroll
        for (int j = 0; j < TOPN; ++j) { bv[j] = DBL_MAX; bi[j] = 0x7fffffff; }
        for (int k = 0; k < CAND; ++k)
            topk_insert<TOPN,double>(bv, bi, dvs[k], dis[k]);
        #pragma unroll
        for (int j = 0; j < TOPN; ++j) {
            out[(size_t)q * TOPN + j] = (float)sqrt(bv[j]);
            out[(size_t)B_DIM * NQ * TOPN + (size_t)q * TOPN + j] = (float)bi[j];
        }
    }
}

extern "C" void kernel_launch(void* const* d_in, const int* in_sizes, int n_in,
                              void* d_out, int out_size, void* d_ws, size_t ws_size,
                              hipStream_t stream) {
    const float* Q    = (const float*)d_in[0];
    const float* C    = (const float*)d_in[1];
    const float* W    = (const float*)d_in[2];
    const float* bias = (const float*)d_in[3];
    float* out = (float*)d_out;

    char* ws = (char*)d_ws;
    double*         P64 = (double*)ws;                                       // 32 MB
    unsigned short* Pbf = (unsigned short*)(ws + (size_t)32 * 1024 * 1024);  //  8 MB
    unsigned short* Cbf = (unsigned short*)(ws + (size_t)40 * 1024 * 1024);  // 128 MB
    float*          qsq = (float*)(ws + (size_t)168 * 1024 * 1024);          // 16 KB
    float*          csq = qsq + 4096;                                        // 256 KB
    int*            pi  = (int*)(csq + 65536);                               // 1.25 MB
    // total ~170 MB of workspace

    proj64_kernel<<<dim3(D_DIM / 64, (B_DIM * NQ) / 64), 256, 0, stream>>>(Q, W, bias, P64);
    pack_c_kernel<<<(B_DIM * NC) / 4, 256, 0, stream>>>(C, Cbf, csq);
    pack_q_kernel<<<(B_DIM * NQ) / 4, 256, 0, stream>>>(P64, Pbf, qsq);
    dist_mfma_kernel<<<dim3(CSPLIT, NQ / QT, B_DIM), 256, 0, stream>>>(Pbf, Cbf, qsq, csq, pi);
    refine_kernel<<<B_DIM * NQ, 256, 0, stream>>>(P64, C, pi, out);
}